// Round 2
// baseline (10514.867 us; speedup 1.0000x reference)
//
#include <hip/hip_runtime.h>
#include <hip/hip_bf16.h>
#include <math.h>

#define ODIM 592002L
#define NB 8

typedef __hip_bfloat16 bf16;
__device__ __forceinline__ float b2f(bf16 x) { return __bfloat162float(x); }
__device__ __forceinline__ bf16 f2b(float x) { return __float2bfloat16(x); }

// ---------------- hypernet: h2 = (hp*W1^T + b1) @ W2^T + b2 ----------------
__global__ __launch_bounds__(256) void hyper_h(
    const float* __restrict__ hp, const float* __restrict__ W1,
    const float* __restrict__ b1, const float* __restrict__ W2,
    const float* __restrict__ b2, float* __restrict__ h2out)
{
    __shared__ float h1[NB][32];
    int t = threadIdx.x;          // 256 = 8 samples x 32 dims
    int b = t >> 5, i = t & 31;
    h1[b][i] = hp[b] * W1[i] + b1[i];
    __syncthreads();
    float acc = b2[i];
    #pragma unroll
    for (int j = 0; j < 32; ++j) acc += h1[b][j] * W2[i * 32 + j];
    h2out[b * 32 + i] = acc;
}

// ------- w = tanh(h2 @ Wo^T + bo) -> bf16, + per-block |w| partials (f32) --
__global__ __launch_bounds__(256) void genw(
    const float* __restrict__ Wo, const float* __restrict__ bo,
    const float* __restrict__ h2, bf16* __restrict__ wfb,
    float* __restrict__ part)
{
    __shared__ float h2s[256];
    __shared__ float red[256];
    int t = threadIdx.x;
    h2s[t] = h2[t];
    __syncthreads();
    long o = (long)blockIdx.x * 256 + t;
    float absacc[NB];
    #pragma unroll
    for (int b = 0; b < NB; ++b) absacc[b] = 0.f;
    if (o < ODIM) {
        float row[32];
        const float4* wp = (const float4*)(Wo + o * 32);
        #pragma unroll
        for (int q = 0; q < 8; ++q) {
            float4 v = wp[q];
            row[q*4+0] = v.x; row[q*4+1] = v.y; row[q*4+2] = v.z; row[q*4+3] = v.w;
        }
        float bias = bo[o];
        #pragma unroll
        for (int b = 0; b < NB; ++b) {
            float acc = bias;
            #pragma unroll
            for (int k = 0; k < 32; ++k) acc += h2s[b*32+k] * row[k];
            float w = tanhf(acc);
            wfb[(long)b * ODIM + o] = f2b(w);
            absacc[b] = fabsf(w);
        }
    }
    for (int b = 0; b < NB; ++b) {
        red[t] = absacc[b];
        __syncthreads();
        for (int s = 128; s > 0; s >>= 1) {
            if (t < s) red[t] += red[t + s];
            __syncthreads();
        }
        if (t == 0) part[(long)blockIdx.x * NB + b] = red[0];
        __syncthreads();
    }
}

__global__ void l1_reduce(const float* __restrict__ part, int nblk,
                          float* __restrict__ out)
{
    int b = threadIdx.x;
    if (b < NB) {
        float s = 0.f;
        for (int i = 0; i < nblk; ++i) s += part[(long)i * NB + b];
        out[b] = s;
    }
}

// ---------------- zf NHWC f32 -> NCHW bf16 ----------------
__global__ __launch_bounds__(256) void zf2bf(const float* __restrict__ zf,
                                             bf16* __restrict__ out)
{
    int i = blockIdx.x * 256 + threadIdx.x;   // over 8*2*65536
    int pix = i & 65535;
    int c = (i >> 16) & 1;
    int b = i >> 17;
    out[i] = f2b(zf[((long)b * 65536 + pix) * 2 + c]);
}

// ---------------- generic 3x3 conv, pad=1, NCHW bf16, 4 oc/block ----------
__global__ __launch_bounds__(256) void conv3x3(
    const bf16* __restrict__ in1, int C1,
    const bf16* __restrict__ in2, int C2,
    int H, int W,
    const bf16* __restrict__ wfb, int koff, int boff,
    bf16* __restrict__ out, int relu)
{
    __shared__ float4 ldsw[128 * 9];     // [ic][tap] -> 4 oc weights (f32)
    float* ldswf = (float*)ldsw;
    const int t = threadIdx.x;
    const int b = blockIdx.z;
    const int ocb = blockIdx.y * 4;
    const int Cin = C1 + C2;
    const int HW = H * W;

    const long wbase = (long)b * ODIM + koff + (long)ocb * Cin * 9;
    const int wcount = 4 * Cin * 9;
    for (int idx = t; idx < wcount; idx += 256) {
        int o = idx / (Cin * 9);
        int rem = idx - o * (Cin * 9);
        ldswf[rem * 4 + o] = b2f(wfb[wbase + (long)o * (Cin * 9) + rem]);
    }
    const long bb = (long)b * ODIM + boff + ocb;
    float acc0 = b2f(wfb[bb]), acc1 = b2f(wfb[bb + 1]),
          acc2 = b2f(wfb[bb + 2]), acc3 = b2f(wfb[bb + 3]);
    __syncthreads();

    const int pix = blockIdx.x * 256 + t;
    const int x = pix % W;
    const int y = pix / W;

    const bf16* s1 = in1 + (long)b * C1 * HW;
    const bf16* s2 = in2 ? in2 + (long)b * C2 * HW : nullptr;

    for (int ic = 0; ic < Cin; ++ic) {
        const bf16* sp = (ic < C1) ? s1 + (long)ic * HW
                                   : s2 + (long)(ic - C1) * HW;
        const float4* wr = ldsw + ic * 9;
        #pragma unroll
        for (int dy = -1; dy <= 1; ++dy) {
            int yy = y + dy;
            if ((unsigned)yy < (unsigned)H) {
                const bf16* rp = sp + (long)yy * W;
                #pragma unroll
                for (int dx = -1; dx <= 1; ++dx) {
                    int xx = x + dx;
                    if ((unsigned)xx < (unsigned)W) {
                        float v = b2f(rp[xx]);
                        float4 w4 = wr[(dy + 1) * 3 + (dx + 1)];
                        acc0 += v * w4.x; acc1 += v * w4.y;
                        acc2 += v * w4.z; acc3 += v * w4.w;
                    }
                }
            }
        }
    }

    if (relu) {
        acc0 = fmaxf(acc0, 0.f); acc1 = fmaxf(acc1, 0.f);
        acc2 = fmaxf(acc2, 0.f); acc3 = fmaxf(acc3, 0.f);
    }
    long ob = ((long)b * 64 + ocb) * HW + pix;
    out[ob] = f2b(acc0);
    out[ob + HW] = f2b(acc1);
    out[ob + 2 * (long)HW] = f2b(acc2);
    out[ob + 3 * (long)HW] = f2b(acc3);
}

// ------- conv12: bilinear-up2(128->256, align_corners) fused into conv ----
// in1 = lo [8,64,128,128] upsampled on the fly (LDS staging per ic),
// in2 = skip [8,64,256,256]. Block = one output row (256 px), 4 oc.
__global__ __launch_bounds__(256) void conv_up256(
    const bf16* __restrict__ lo, const bf16* __restrict__ skip,
    const bf16* __restrict__ wfb, int koff, int boff,
    bf16* __restrict__ out)
{
    __shared__ float4 ldsw[128 * 9];
    __shared__ float ups[3][264];
    float* ldswf = (float*)ldsw;
    const int t = threadIdx.x;
    const int b = blockIdx.z;
    const int ocb = blockIdx.y * 4;
    const int y = blockIdx.x;            // output row 0..255
    const int Cin = 128;

    const long wbase = (long)b * ODIM + koff + (long)ocb * Cin * 9;
    for (int idx = t; idx < 4 * Cin * 9; idx += 256) {
        int o = idx / (Cin * 9);
        int rem = idx - o * (Cin * 9);
        ldswf[rem * 4 + o] = b2f(wfb[wbase + (long)o * (Cin * 9) + rem]);
    }
    const long bb = (long)b * ODIM + boff + ocb;
    float acc0 = b2f(wfb[bb]), acc1 = b2f(wfb[bb + 1]),
          acc2 = b2f(wfb[bb + 2]), acc3 = b2f(wfb[bb + 3]);

    const int x = t;
    const bf16* lob = lo + (long)b * 64 * 16384;
    const bf16* skb = skip + (long)b * 64 * 65536;
    const float sc = 127.f / 255.f;

    // upsampled input channels
    for (int ic = 0; ic < 64; ++ic) {
        __syncthreads();
        const bf16* L = lob + (long)ic * 16384;
        for (int idx = t; idx < 774; idx += 256) {   // 3 rows x 258 cols
            int r = idx / 258, cc = idx - r * 258;
            int yy = y + r - 1, xx = cc - 1;
            float v = 0.f;
            if ((unsigned)yy < 256u && (unsigned)xx < 256u) {
                float ys = yy * sc, xs = xx * sc;
                int y0 = (int)ys; int y1 = min(y0 + 1, 127);
                float wy = ys - (float)y0;
                int x0 = (int)xs; int x1 = min(x0 + 1, 127);
                float wx = xs - (float)x0;
                const bf16* p0 = L + y0 * 128;
                const bf16* p1 = L + y1 * 128;
                v = (b2f(p0[x0]) * (1.f - wy) + b2f(p1[x0]) * wy) * (1.f - wx)
                  + (b2f(p0[x1]) * (1.f - wy) + b2f(p1[x1]) * wy) * wx;
            }
            ups[r][cc] = v;
        }
        __syncthreads();
        const float4* wr = ldsw + ic * 9;
        #pragma unroll
        for (int dy = 0; dy < 3; ++dy) {
            #pragma unroll
            for (int dx = 0; dx < 3; ++dx) {
                float v = ups[dy][x + dx];
                float4 w4 = wr[dy * 3 + dx];
                acc0 += v * w4.x; acc1 += v * w4.y;
                acc2 += v * w4.z; acc3 += v * w4.w;
            }
        }
    }

    // skip channels (regular taps @256)
    for (int ic = 0; ic < 64; ++ic) {
        const bf16* sp = skb + (long)ic * 65536;
        const float4* wr = ldsw + (64 + ic) * 9;
        #pragma unroll
        for (int dy = -1; dy <= 1; ++dy) {
            int yy = y + dy;
            if ((unsigned)yy < 256u) {
                const bf16* rp = sp + (long)yy * 256;
                #pragma unroll
                for (int dx = -1; dx <= 1; ++dx) {
                    int xx = x + dx;
                    if ((unsigned)xx < 256u) {
                        float v = b2f(rp[xx]);
                        float4 w4 = wr[(dy + 1) * 3 + (dx + 1)];
                        acc0 += v * w4.x; acc1 += v * w4.y;
                        acc2 += v * w4.z; acc3 += v * w4.w;
                    }
                }
            }
        }
    }

    acc0 = fmaxf(acc0, 0.f); acc1 = fmaxf(acc1, 0.f);
    acc2 = fmaxf(acc2, 0.f); acc3 = fmaxf(acc3, 0.f);
    long ob = ((long)b * 64 + ocb) * 65536 + y * 256 + x;
    out[ob] = f2b(acc0);
    out[ob + 65536] = f2b(acc1);
    out[ob + 2 * 65536] = f2b(acc2);
    out[ob + 3 * 65536] = f2b(acc3);
}

// ---------------- 2x2 maxpool (bf16) ----------------
__global__ __launch_bounds__(256) void maxpool(
    const bf16* __restrict__ in, bf16* __restrict__ out,
    int C, int H, int W, int n)
{
    int i = blockIdx.x * 256 + threadIdx.x;
    if (i >= n) return;
    int Wo = W >> 1, Ho = H >> 1;
    int x = i % Wo; int tmp = i / Wo;
    int y = tmp % Ho; tmp /= Ho;
    int c = tmp % C; int b = tmp / C;
    const bf16* p = in + (((long)b * C + c) * H + 2 * y) * W + 2 * x;
    float v = fmaxf(fmaxf(b2f(p[0]), b2f(p[1])),
                    fmaxf(b2f(p[W]), b2f(p[W + 1])));
    out[i] = f2b(v);
}

// ---------------- 2x bilinear upsample, align_corners=True (bf16) ---------
__global__ __launch_bounds__(256) void up2(
    const bf16* __restrict__ in, bf16* __restrict__ out,
    int C, int h, int w, int n)
{
    int i = blockIdx.x * 256 + threadIdx.x;
    if (i >= n) return;
    int Wo = 2 * w, Ho = 2 * h;
    int ox = i % Wo; int tmp = i / Wo;
    int oy = tmp % Ho; tmp /= Ho;
    int c = tmp % C; int b = tmp / C;
    float ys = oy * (float)(h - 1) / (float)(Ho - 1);
    float xs = ox * (float)(w - 1) / (float)(Wo - 1);
    int y0 = (int)floorf(ys); int y1 = min(y0 + 1, h - 1);
    float wy = ys - (float)y0;
    int x0 = (int)floorf(xs); int x1 = min(x0 + 1, w - 1);
    float wx = xs - (float)x0;
    const bf16* p = in + ((long)b * C + c) * h * w;
    float v = (b2f(p[y0 * w + x0]) * (1.f - wy) + b2f(p[y1 * w + x0]) * wy) * (1.f - wx)
            + (b2f(p[y0 * w + x1]) * (1.f - wy) + b2f(p[y1 * w + x1]) * wy) * wx;
    out[i] = f2b(v);
}

// ---------- final 1x1 conv (64->2) + residual + NHWC f32 store ------------
__global__ __launch_bounds__(256) void final_conv(
    const bf16* __restrict__ in, const bf16* __restrict__ wfb,
    const float* __restrict__ zf, float* __restrict__ out)
{
    __shared__ float wsh[128];
    __shared__ float bsh[2];
    int t = threadIdx.x;
    int i = blockIdx.x * 256 + t;
    int pix = i & 65535;
    int b = i >> 16;
    const long wb = (long)b * ODIM;
    if (t < 128) wsh[t] = b2f(wfb[wb + 590976 + t]);
    if (t < 2)  bsh[t] = b2f(wfb[wb + 592000 + t]);
    __syncthreads();
    const bf16* p = in + (long)b * 64 * 65536 + pix;
    float a0 = bsh[0], a1 = bsh[1];
    #pragma unroll
    for (int c = 0; c < 64; ++c) {
        float v = b2f(p[(long)c * 65536]);
        a0 += v * wsh[c];
        a1 += v * wsh[64 + c];
    }
    long zi = ((long)b * 65536 + pix) * 2;
    out[zi]     = zf[zi] + a0;
    out[zi + 1] = zf[zi + 1] + a1;
}

extern "C" void kernel_launch(void* const* d_in, const int* in_sizes, int n_in,
                              void* d_out, int out_size, void* d_ws, size_t ws_size,
                              hipStream_t stream)
{
    (void)in_sizes; (void)n_in; (void)out_size; (void)ws_size;
    const float* zf = (const float*)d_in[0];
    const float* hp = (const float*)d_in[2];
    const float* W1 = (const float*)d_in[3];
    const float* b1 = (const float*)d_in[4];
    const float* W2 = (const float*)d_in[5];
    const float* b2 = (const float*)d_in[6];
    const float* Wo = (const float*)d_in[7];
    const float* bo = (const float*)d_in[8];
    float* out = (float*)d_out;

    // ---- workspace carve (total ~212 MB) ----
    char* base = (char*)d_ws;
    float* h2  = (float*)base;  base += 1024;            // 256 f32
    float* part = (float*)base; base += 18504 * 4;       // 2313*8 f32
    bf16* wfb  = (bf16*)base;   base += 4736016L * 2;    // 8*592002 bf16
    bf16* ZB   = (bf16*)base;   base += 1048576L * 2;    // zf NCHW bf16
    bf16* Y256 = (bf16*)base;   base += 33554432L * 2;   // 8*64*256*256
    bf16* C1   = (bf16*)base;   base += 33554432L * 2;
    bf16* P128 = (bf16*)base;   base += 8388608L * 2;    // 8*64*128*128
    bf16* Q128 = (bf16*)base;   base += 8388608L * 2;
    bf16* C2   = (bf16*)base;   base += 8388608L * 2;
    bf16* A64  = (bf16*)base;   base += 2097152L * 2;    // 8*64*64*64
    bf16* B64  = (bf16*)base;   base += 2097152L * 2;
    bf16* C3   = (bf16*)base;   base += 2097152L * 2;
    bf16* A32  = (bf16*)base;   base += 524288L * 2;     // 8*64*32*32
    bf16* B32  = (bf16*)base;   base += 524288L * 2;
    bf16* C4   = (bf16*)base;   base += 524288L * 2;

    hyper_h<<<1, 256, 0, stream>>>(hp, W1, b1, W2, b2, h2);
    const int ngb = (int)((ODIM + 255) / 256);   // 2313
    genw<<<ngb, 256, 0, stream>>>(Wo, bo, h2, wfb, part);
    l1_reduce<<<1, 64, 0, stream>>>(part, ngb, out + 1048576);
    zf2bf<<<4096, 256, 0, stream>>>(zf, ZB);

    const int K0=0, K1=1152, K2=38016, K3=74880, K4=111744, K5=148608,
              K6=185472, K7=222336, K8=259200, K9=332928, K10=369792,
              K11=443520, K12=480384, K13=554112;
    const int BB = 591104;  // bias base; bias_i = BB + 64*i

    // ---- encoder ----
    conv3x3<<<dim3(256, 16, 8), 256, 0, stream>>>(
        ZB, 2, nullptr, 0, 256, 256, wfb, K0, BB + 0, Y256, 1);
    conv3x3<<<dim3(256, 16, 8), 256, 0, stream>>>(
        Y256, 64, nullptr, 0, 256, 256, wfb, K1, BB + 64, C1, 1);
    maxpool<<<8388608 / 256, 256, 0, stream>>>(C1, P128, 64, 256, 256, 8388608);
    conv3x3<<<dim3(64, 16, 8), 256, 0, stream>>>(
        P128, 64, nullptr, 0, 128, 128, wfb, K2, BB + 128, Q128, 1);
    conv3x3<<<dim3(64, 16, 8), 256, 0, stream>>>(
        Q128, 64, nullptr, 0, 128, 128, wfb, K3, BB + 192, C2, 1);
    maxpool<<<2097152 / 256, 256, 0, stream>>>(C2, A64, 64, 128, 128, 2097152);
    conv3x3<<<dim3(16, 16, 8), 256, 0, stream>>>(
        A64, 64, nullptr, 0, 64, 64, wfb, K4, BB + 256, B64, 1);
    conv3x3<<<dim3(16, 16, 8), 256, 0, stream>>>(
        B64, 64, nullptr, 0, 64, 64, wfb, K5, BB + 320, C3, 1);
    maxpool<<<524288 / 256, 256, 0, stream>>>(C3, A32, 64, 64, 64, 524288);
    conv3x3<<<dim3(4, 16, 8), 256, 0, stream>>>(
        A32, 64, nullptr, 0, 32, 32, wfb, K6, BB + 384, B32, 1);
    conv3x3<<<dim3(4, 16, 8), 256, 0, stream>>>(
        B32, 64, nullptr, 0, 32, 32, wfb, K7, BB + 448, C4, 1);

    // ---- decoder ----
    up2<<<2097152 / 256, 256, 0, stream>>>(C4, A64, 64, 32, 32, 2097152);
    conv3x3<<<dim3(16, 16, 8), 256, 0, stream>>>(
        A64, 64, C3, 64, 64, 64, wfb, K8, BB + 512, B64, 1);
    conv3x3<<<dim3(16, 16, 8), 256, 0, stream>>>(
        B64, 64, nullptr, 0, 64, 64, wfb, K9, BB + 576, A64, 1);
    up2<<<8388608 / 256, 256, 0, stream>>>(A64, P128, 64, 64, 64, 8388608);
    conv3x3<<<dim3(64, 16, 8), 256, 0, stream>>>(
        P128, 64, C2, 64, 128, 128, wfb, K10, BB + 640, Q128, 1);
    conv3x3<<<dim3(64, 16, 8), 256, 0, stream>>>(
        Q128, 64, nullptr, 0, 128, 128, wfb, K11, BB + 704, P128, 1);
    conv_up256<<<dim3(256, 16, 8), 256, 0, stream>>>(
        P128, C1, wfb, K12, BB + 768, Y256);
    conv3x3<<<dim3(256, 16, 8), 256, 0, stream>>>(
        Y256, 64, nullptr, 0, 256, 256, wfb, K13, BB + 832, C1, 1);

    final_conv<<<2048, 256, 0, stream>>>(C1, wfb, zf, out);
}

// Round 3
// 1168.597 us; speedup vs baseline: 8.9979x; 8.9979x over previous
//
#include <hip/hip_runtime.h>
#include <hip/hip_bf16.h>
#include <math.h>

#define ODIM 592002L
#define WRB  589824L
#define NB 8

typedef __hip_bfloat16 bf16;
typedef __bf16  bf16x8 __attribute__((ext_vector_type(8)));
typedef float   f32x16 __attribute__((ext_vector_type(16)));
typedef short   s16x8  __attribute__((ext_vector_type(8)));

__device__ __forceinline__ float b2f(bf16 x) { return __bfloat162float(x); }
__device__ __forceinline__ bf16 f2b(float x) { return __float2bfloat16(x); }
__device__ __forceinline__ bf16x8 bzero() { return __builtin_bit_cast(bf16x8, (s16x8)0); }

// ---------------- hypernet: h2 = (hp*W1^T + b1) @ W2^T + b2 ----------------
__global__ __launch_bounds__(256) void hyper_h(
    const float* __restrict__ hp, const float* __restrict__ W1,
    const float* __restrict__ b1, const float* __restrict__ W2,
    const float* __restrict__ b2, float* __restrict__ h2out)
{
    __shared__ float h1[NB][32];
    int t = threadIdx.x;
    int b = t >> 5, i = t & 31;
    h1[b][i] = hp[b] * W1[i] + b1[i];
    __syncthreads();
    float acc = b2[i];
    #pragma unroll
    for (int j = 0; j < 32; ++j) acc += h1[b][j] * W2[i * 32 + j];
    h2out[b * 32 + i] = acc;
}

// ------- w = tanh(h2 @ Wo^T + bo) -> bf16, + per-block |w| partials (f32) --
__global__ __launch_bounds__(256) void genw(
    const float* __restrict__ Wo, const float* __restrict__ bo,
    const float* __restrict__ h2, bf16* __restrict__ wfb,
    float* __restrict__ part)
{
    __shared__ float h2s[256];
    __shared__ float red[256];
    int t = threadIdx.x;
    h2s[t] = h2[t];
    __syncthreads();
    long o = (long)blockIdx.x * 256 + t;
    float absacc[NB];
    #pragma unroll
    for (int b = 0; b < NB; ++b) absacc[b] = 0.f;
    if (o < ODIM) {
        float row[32];
        const float4* wp = (const float4*)(Wo + o * 32);
        #pragma unroll
        for (int q = 0; q < 8; ++q) {
            float4 v = wp[q];
            row[q*4+0] = v.x; row[q*4+1] = v.y; row[q*4+2] = v.z; row[q*4+3] = v.w;
        }
        float bias = bo[o];
        #pragma unroll
        for (int b = 0; b < NB; ++b) {
            float acc = bias;
            #pragma unroll
            for (int k = 0; k < 32; ++k) acc += h2s[b*32+k] * row[k];
            float w = tanhf(acc);
            wfb[(long)b * ODIM + o] = f2b(w);
            absacc[b] = fabsf(w);
        }
    }
    for (int b = 0; b < NB; ++b) {
        red[t] = absacc[b];
        __syncthreads();
        for (int s = 128; s > 0; s >>= 1) {
            if (t < s) red[t] += red[t + s];
            __syncthreads();
        }
        if (t == 0) part[(long)blockIdx.x * NB + b] = red[0];
        __syncthreads();
    }
}

__global__ __launch_bounds__(256) void l1_reduce(
    const float* __restrict__ part, int nblk, float* __restrict__ outp)
{
    __shared__ float red[256];
    int t = threadIdx.x; int b = t & 7, ch = t >> 3;
    float s = 0.f;
    for (int i = ch; i < nblk; i += 32) s += part[(long)i * 8 + b];
    red[t] = s;
    __syncthreads();
    for (int st = 128; st >= 8; st >>= 1) {
        if (t < st) red[t] += red[t + st];
        __syncthreads();
    }
    if (t < 8) outp[t] = red[t];
}

// ------- repack weights: wfb [oc][ic_full][tap] -> wrep [oc][pass][tap][ic] -
__global__ __launch_bounds__(256) void repack(
    const bf16* __restrict__ wfb, bf16* __restrict__ wr,
    int koff, int Cinfull, long roff, int K)
{
    int idx = blockIdx.x * 256 + threadIdx.x;
    int b = blockIdx.y;
    if (idx >= 64 * K) return;
    int oc = idx / K, kk = idx - oc * K;
    int pass = kk / 576;
    int kl = kk - pass * 576;
    int tap = kl >> 6, ic = kl & 63;
    int icf = pass * 64 + ic;
    wr[(long)b * WRB + roff + idx] =
        wfb[(long)b * ODIM + koff + ((long)oc * Cinfull + icf) * 9 + tap];
}

// ---------------- LDS staging: PLAIN(0) / POOL(1) / UP2(2) ----------------
template<int TR, int TC, int MODE>
__device__ __forceinline__ void stage_tile(
    const bf16* __restrict__ src, int Hc, int Wc, int y0, int x0,
    bf16* lin, int t)
{
    const int XL = TC + 2;
    const int total = (TR + 2) * XL * 8;
    for (int idx = t; idx < total; idx += 256) {
        const int g = idx & 7;
        const int rem = idx >> 3;
        const int xl = rem % XL;
        const int gy = y0 + rem / XL - 1, gx = x0 + xl - 1;
        bf16x8 v = bzero();
        if ((unsigned)gy < (unsigned)Hc && (unsigned)gx < (unsigned)Wc) {
            if constexpr (MODE == 0) {
                v = *(const bf16x8*)(src + (((long)gy * Wc) + gx) * 64 + g * 8);
            } else if constexpr (MODE == 1) {
                const int Ws = Wc * 2;
                const bf16* p = src + (((long)(gy*2) * Ws) + gx*2) * 64 + g * 8;
                bf16x8 aa = *(const bf16x8*)p;
                bf16x8 bb = *(const bf16x8*)(p + 64);
                bf16x8 cc = *(const bf16x8*)(p + (long)Ws * 64);
                bf16x8 dd = *(const bf16x8*)(p + (long)Ws * 64 + 64);
                #pragma unroll
                for (int j = 0; j < 8; ++j) {
                    float m = fmaxf(fmaxf((float)aa[j], (float)bb[j]),
                                    fmaxf((float)cc[j], (float)dd[j]));
                    v[j] = (__bf16)m;
                }
            } else {
                const int Hs = Hc >> 1, Ws = Wc >> 1;
                const float sy = (float)(Hs - 1) / (float)(Hc - 1);
                const float sx = (float)(Ws - 1) / (float)(Wc - 1);
                float ys = gy * sy, xs = gx * sx;
                int yy0 = (int)ys, xx0 = (int)xs;
                int yy1 = min(yy0 + 1, Hs - 1), xx1 = min(xx0 + 1, Ws - 1);
                float wy = ys - (float)yy0, wx = xs - (float)xx0;
                bf16x8 q00 = *(const bf16x8*)(src + ((long)yy0*Ws + xx0)*64 + g*8);
                bf16x8 q01 = *(const bf16x8*)(src + ((long)yy0*Ws + xx1)*64 + g*8);
                bf16x8 q10 = *(const bf16x8*)(src + ((long)yy1*Ws + xx0)*64 + g*8);
                bf16x8 q11 = *(const bf16x8*)(src + ((long)yy1*Ws + xx1)*64 + g*8);
                #pragma unroll
                for (int j = 0; j < 8; ++j) {
                    float r0 = (float)q00[j]*(1.f-wx) + (float)q01[j]*wx;
                    float r1 = (float)q10[j]*(1.f-wx) + (float)q11[j]*wx;
                    v[j] = (__bf16)(r0*(1.f-wy) + r1*wy);
                }
            }
        }
        long byte = (((long)rem) * 128 + g * 16) ^ ((xl & 7) << 4);
        *(bf16x8*)((char*)lin + byte) = v;
    }
}

// ---------------- MFMA implicit-GEMM 3x3 conv, 64 oc, NHWC bf16 -----------
// Block: 64 oc x (TR*TC) pixels. 4 waves; wave = 1 pixel-subtile (32px), 2 oc-subtiles.
// K-order: pass*576 + tap*64 + ic. src2 (concat skip) = second K-pass.
template<int TR, int TC, int MODE>
__global__ __launch_bounds__(256) void conv_mfma(
    const bf16* __restrict__ src1, const bf16* __restrict__ src2,
    int Hc, int Wc,
    const bf16* __restrict__ wr, long roff, int K,
    const bf16* __restrict__ wfb, int boff,
    bf16* __restrict__ outp)
{
    const int XL = TC + 2;
    __shared__ bf16 lin[(TR + 2) * (TC + 2) * 64];
    const int t = threadIdx.x;
    const int lane = t & 63;
    const int w = t >> 6;
    const int b = blockIdx.z;
    const int y0 = blockIdx.y * TR;
    const int x0 = blockIdx.x * TC;

    const int nx = TC / 32;
    const int rw = w / nx;
    const int cb = (w % nx) * 32;
    const int lx = cb + (lane & 31);

    f32x16 acc0 = {};
    f32x16 acc1 = {};

    const bf16* wl = wr + (long)b * WRB + roff;
    const bf16* pa = wl + (long)(lane & 31) * K + (lane >> 5) * 8;

    int xl128[3], swz[3];
    #pragma unroll
    for (int d = 0; d < 3; ++d) {
        int xl = lx + d;
        xl128[d] = xl * 128;
        swz[d] = (xl & 7) << 4;
    }
    const int icbl = (lane >> 5) * 16;   // lane k-group byte offset

    auto kpass = [&](int passoff) {
        #pragma unroll
        for (int tap = 0; tap < 9; ++tap) {
            const int dy = tap / 3, dxi = tap % 3;
            const int rb = (rw + dy) * (XL * 128);
            #pragma unroll
            for (int k4 = 0; k4 < 4; ++k4) {
                const int ic0 = k4 * 16;
                const int icb = ic0 * 2 + icbl;
                const int a_ = rb + xl128[dxi] + (icb ^ swz[dxi]);
                bf16x8 bfrag = *(const bf16x8*)((const char*)lin + a_);
                const bf16* pk = pa + passoff + tap * 64 + ic0;
                bf16x8 a0 = *(const bf16x8*)pk;
                bf16x8 a1 = *(const bf16x8*)(pk + 32 * (long)K);
                acc0 = __builtin_amdgcn_mfma_f32_32x32x16_bf16(a0, bfrag, acc0, 0, 0, 0);
                acc1 = __builtin_amdgcn_mfma_f32_32x32x16_bf16(a1, bfrag, acc1, 0, 0, 0);
            }
        }
    };

    stage_tile<TR, TC, MODE>(src1, Hc, Wc, y0, x0, lin, t);
    __syncthreads();
    kpass(0);
    if (src2) {
        __syncthreads();
        stage_tile<TR, TC, 0>(src2, Hc, Wc, y0, x0, lin, t);
        __syncthreads();
        kpass(576);
    }

    // ---- epilogue: acc -> LDS [pix][oc] (swizzled) -> coalesced store ----
    __syncthreads();
    const long bb = (long)b * ODIM + boff;
    const int pixidx = rw * TC + (cb + (lane & 31));
    const int psw = (pixidx & 7) << 4;
    #pragma unroll
    for (int ocs = 0; ocs < 2; ++ocs) {
        const f32x16& A = ocs ? acc1 : acc0;
        #pragma unroll
        for (int q = 0; q < 4; ++q) {
            const int oc0 = ocs * 32 + 8 * q + 4 * (lane >> 5);
            ushort4 pk;
            float v0 = fmaxf(A[4*q+0] + b2f(wfb[bb + oc0 + 0]), 0.f);
            float v1 = fmaxf(A[4*q+1] + b2f(wfb[bb + oc0 + 1]), 0.f);
            float v2 = fmaxf(A[4*q+2] + b2f(wfb[bb + oc0 + 2]), 0.f);
            float v3 = fmaxf(A[4*q+3] + b2f(wfb[bb + oc0 + 3]), 0.f);
            pk.x = __builtin_bit_cast(unsigned short, f2b(v0));
            pk.y = __builtin_bit_cast(unsigned short, f2b(v1));
            pk.z = __builtin_bit_cast(unsigned short, f2b(v2));
            pk.w = __builtin_bit_cast(unsigned short, f2b(v3));
            long byte = ((long)pixidx * 128 + oc0 * 2) ^ psw;
            *(ushort4*)((char*)lin + byte) = pk;
        }
    }
    __syncthreads();
    bf16* outt = outp + (((long)b * Hc + y0) * Wc + x0) * 64;
    const int TPB = TR * TC * 128;
    for (int off = t * 16; off < TPB; off += 4096) {
        int pix = off >> 7;
        long byte = (long)off ^ ((pix & 7) << 4);
        bf16x8 v = *(const bf16x8*)((const char*)lin + byte);
        *(bf16x8*)((char*)outt + off) = v;
    }
}

// ---------------- conv0: 2->64 @256, zf f32 NHWC direct -------------------
__global__ __launch_bounds__(256) void conv0_k(
    const float* __restrict__ zf, const bf16* __restrict__ wfb,
    bf16* __restrict__ outp)
{
    __shared__ float wsh[2][9][64];
    __shared__ float bsh[64];
    const int t = threadIdx.x;
    const int b = blockIdx.z;
    const long wb = (long)b * ODIM;
    for (int i = t; i < 1152; i += 256) {
        int oc = i / 18, r2 = i % 18, ic = r2 / 9, tap = r2 % 9;
        wsh[ic][tap][oc] = b2f(wfb[wb + i]);
    }
    if (t < 64) bsh[t] = b2f(wfb[wb + 591104 + t]);
    __syncthreads();
    const int pl = t >> 3, g = t & 7;
    const int pix = blockIdx.x * 32 + pl;
    const int y = pix >> 8, x = pix & 255;
    float acc[8];
    #pragma unroll
    for (int j = 0; j < 8; ++j) acc[j] = bsh[g * 8 + j];
    const float* zb = zf + (long)b * 131072;
    #pragma unroll
    for (int dy = 0; dy < 3; ++dy) {
        int yy = y + dy - 1;
        if ((unsigned)yy >= 256u) continue;
        #pragma unroll
        for (int dx = 0; dx < 3; ++dx) {
            int xx = x + dx - 1;
            if ((unsigned)xx >= 256u) continue;
            const float* p = zb + ((long)yy * 256 + xx) * 2;
            float v0 = p[0], v1 = p[1];
            int tap = dy * 3 + dx;
            #pragma unroll
            for (int j = 0; j < 8; ++j)
                acc[j] += v0 * wsh[0][tap][g*8+j] + v1 * wsh[1][tap][g*8+j];
        }
    }
    bf16x8 v;
    #pragma unroll
    for (int j = 0; j < 8; ++j) v[j] = (__bf16)fmaxf(acc[j], 0.f);
    *(bf16x8*)(outp + ((long)b * 65536 + pix) * 64 + g * 8) = v;
}

// ---------- final 1x1 conv (64->2) + residual + NHWC f32 store ------------
__global__ __launch_bounds__(256) void final_k(
    const bf16* __restrict__ X, const bf16* __restrict__ wfb,
    const float* __restrict__ zf, float* __restrict__ outp)
{
    __shared__ float wsh[128];
    __shared__ float bsh[2];
    const int t = threadIdx.x;
    const int i = blockIdx.x * 256 + t;
    const int pix = i & 65535;
    const int b = i >> 16;
    const long wb = (long)b * ODIM;
    if (t < 128) wsh[t] = b2f(wfb[wb + 590976 + t]);
    if (t < 2) bsh[t] = b2f(wfb[wb + 592000 + t]);
    __syncthreads();
    const bf16* p = X + ((long)b * 65536 + pix) * 64;
    float a0 = bsh[0], a1 = bsh[1];
    #pragma unroll
    for (int gq = 0; gq < 8; ++gq) {
        bf16x8 v = *(const bf16x8*)(p + gq * 8);
        #pragma unroll
        for (int j = 0; j < 8; ++j) {
            float f = (float)v[j];
            a0 += f * wsh[gq*8 + j];
            a1 += f * wsh[64 + gq*8 + j];
        }
    }
    long zi = ((long)b * 65536 + pix) * 2;
    outp[zi] = zf[zi] + a0;
    outp[zi + 1] = zf[zi + 1] + a1;
}

extern "C" void kernel_launch(void* const* d_in, const int* in_sizes, int n_in,
                              void* d_out, int out_size, void* d_ws, size_t ws_size,
                              hipStream_t stream)
{
    (void)in_sizes; (void)n_in; (void)out_size; (void)ws_size;
    const float* zf = (const float*)d_in[0];
    const float* hp = (const float*)d_in[2];
    const float* W1 = (const float*)d_in[3];
    const float* b1 = (const float*)d_in[4];
    const float* W2 = (const float*)d_in[5];
    const float* b2 = (const float*)d_in[6];
    const float* Wo = (const float*)d_in[7];
    const float* bo = (const float*)d_in[8];
    float* out = (float*)d_out;

    // ---- workspace carve (~218 MB) ----
    char* base = (char*)d_ws;
    float* h2   = (float*)base;  base += 1024;
    float* part = (float*)base;  base += 18504L * 4 + 32;
    bf16* wfb   = (bf16*)base;   base += 4736016L * 2 + 32;   // tanh weights (flat)
    bf16* WREP  = (bf16*)base;   base += 4718592L * 2;        // repacked conv weights
    bf16* Y256  = (bf16*)base;   base += 33554432L * 2;       // 8*256*256*64
    bf16* C1s   = (bf16*)base;   base += 33554432L * 2;
    bf16* D128a = (bf16*)base;   base += 8388608L * 2;        // 8*128*128*64
    bf16* C2s   = (bf16*)base;   base += 8388608L * 2;
    bf16* X128  = (bf16*)base;   base += 8388608L * 2;
    bf16* E64a  = (bf16*)base;   base += 2097152L * 2;        // 8*64*64*64
    bf16* C3s   = (bf16*)base;   base += 2097152L * 2;
    bf16* X64   = (bf16*)base;   base += 2097152L * 2;
    bf16* F32a  = (bf16*)base;   base += 524288L * 2;         // 8*32*32*64
    bf16* C4    = (bf16*)base;   base += 524288L * 2;

    hyper_h<<<1, 256, 0, stream>>>(hp, W1, b1, W2, b2, h2);
    const int ngb = (int)((ODIM + 255) / 256);   // 2313
    genw<<<ngb, 256, 0, stream>>>(Wo, bo, h2, wfb, part);
    l1_reduce<<<1, 256, 0, stream>>>(part, ngb, out + 1048576);

    // flat kernel offsets in wfb
    const int K1=1152, K2=38016, K3=74880, K4=111744, K5=148608,
              K6=185472, K7=222336, K8=259200, K9=332928, K10=369792,
              K11=443520, K12=480384, K13=554112;
    const int BB = 591104;
    // repacked offsets
    const long R1=0, R2=36864, R3=73728, R4=110592, R5=147456, R6=184320,
               R7=221184, R8=258048, R9=331776, R10=368640, R11=442368,
               R12=479232, R13=552960;

    // repack (single: K=576 Cin=64; dual: K=1152 Cin=128)
    repack<<<dim3(144, 8), 256, 0, stream>>>(wfb, WREP, K1, 64, R1, 576);
    repack<<<dim3(144, 8), 256, 0, stream>>>(wfb, WREP, K2, 64, R2, 576);
    repack<<<dim3(144, 8), 256, 0, stream>>>(wfb, WREP, K3, 64, R3, 576);
    repack<<<dim3(144, 8), 256, 0, stream>>>(wfb, WREP, K4, 64, R4, 576);
    repack<<<dim3(144, 8), 256, 0, stream>>>(wfb, WREP, K5, 64, R5, 576);
    repack<<<dim3(144, 8), 256, 0, stream>>>(wfb, WREP, K6, 64, R6, 576);
    repack<<<dim3(144, 8), 256, 0, stream>>>(wfb, WREP, K7, 64, R7, 576);
    repack<<<dim3(288, 8), 256, 0, stream>>>(wfb, WREP, K8, 128, R8, 1152);
    repack<<<dim3(144, 8), 256, 0, stream>>>(wfb, WREP, K9, 64, R9, 576);
    repack<<<dim3(288, 8), 256, 0, stream>>>(wfb, WREP, K10, 128, R10, 1152);
    repack<<<dim3(144, 8), 256, 0, stream>>>(wfb, WREP, K11, 64, R11, 576);
    repack<<<dim3(288, 8), 256, 0, stream>>>(wfb, WREP, K12, 128, R12, 1152);
    repack<<<dim3(144, 8), 256, 0, stream>>>(wfb, WREP, K13, 64, R13, 576);

    conv0_k<<<dim3(2048, 1, 8), 256, 0, stream>>>(zf, wfb, Y256);

    // encoder
    conv_mfma<1,128,0><<<dim3(2,256,8), 256, 0, stream>>>(Y256, nullptr, 256,256, WREP, R1, 576, wfb, BB+64,  C1s);
    conv_mfma<1,128,1><<<dim3(1,128,8), 256, 0, stream>>>(C1s,  nullptr, 128,128, WREP, R2, 576, wfb, BB+128, D128a);
    conv_mfma<1,128,0><<<dim3(1,128,8), 256, 0, stream>>>(D128a,nullptr, 128,128, WREP, R3, 576, wfb, BB+192, C2s);
    conv_mfma<2,64,1> <<<dim3(1,32,8),  256, 0, stream>>>(C2s,  nullptr, 64,64,   WREP, R4, 576, wfb, BB+256, E64a);
    conv_mfma<2,64,0> <<<dim3(1,32,8),  256, 0, stream>>>(E64a, nullptr, 64,64,   WREP, R5, 576, wfb, BB+320, C3s);
    conv_mfma<4,32,1> <<<dim3(1,8,8),   256, 0, stream>>>(C3s,  nullptr, 32,32,   WREP, R6, 576, wfb, BB+384, F32a);
    conv_mfma<4,32,0> <<<dim3(1,8,8),   256, 0, stream>>>(F32a, nullptr, 32,32,   WREP, R7, 576, wfb, BB+448, C4);
    // decoder (UP fused into staging; concat = 2nd K-pass)
    conv_mfma<2,64,2> <<<dim3(1,32,8),  256, 0, stream>>>(C4,   C3s, 64,64,   WREP, R8,  1152, wfb, BB+512, E64a);
    conv_mfma<2,64,0> <<<dim3(1,32,8),  256, 0, stream>>>(E64a, nullptr, 64,64, WREP, R9, 576, wfb, BB+576, X64);
    conv_mfma<1,128,2><<<dim3(1,128,8), 256, 0, stream>>>(X64,  C2s, 128,128, WREP, R10, 1152, wfb, BB+640, D128a);
    conv_mfma<1,128,0><<<dim3(1,128,8), 256, 0, stream>>>(D128a,nullptr,128,128, WREP, R11, 576, wfb, BB+704, X128);
    conv_mfma<1,128,2><<<dim3(2,256,8), 256, 0, stream>>>(X128, C1s, 256,256, WREP, R12, 1152, wfb, BB+768, Y256);
    conv_mfma<1,128,0><<<dim3(2,256,8), 256, 0, stream>>>(Y256, nullptr,256,256, WREP, R13, 576, wfb, BB+832, C1s);

    final_k<<<dim3(2048), 256, 0, stream>>>(C1s, wfb, zf, out);
}

// Round 4
// 789.445 us; speedup vs baseline: 13.3193x; 1.4803x over previous
//
#include <hip/hip_runtime.h>
#include <hip/hip_bf16.h>
#include <math.h>

#define ODIM 592002L
#define WRB  589824L
#define NB 8

typedef __hip_bfloat16 bf16;
typedef __bf16  bf16x8 __attribute__((ext_vector_type(8)));
typedef float   f32x16 __attribute__((ext_vector_type(16)));
typedef short   s16x8  __attribute__((ext_vector_type(8)));

__device__ __forceinline__ float b2f(bf16 x) { return __bfloat162float(x); }
__device__ __forceinline__ bf16 f2b(float x) { return __float2bfloat16(x); }
__device__ __forceinline__ bf16x8 bzero() { return __builtin_bit_cast(bf16x8, (s16x8)0); }

// ---------------- hypernet: h2 = (hp*W1^T + b1) @ W2^T + b2 ----------------
__global__ __launch_bounds__(256) void hyper_h(
    const float* __restrict__ hp, const float* __restrict__ W1,
    const float* __restrict__ b1, const float* __restrict__ W2,
    const float* __restrict__ b2, float* __restrict__ h2out)
{
    __shared__ float h1[NB][32];
    int t = threadIdx.x;
    int b = t >> 5, i = t & 31;
    h1[b][i] = hp[b] * W1[i] + b1[i];
    __syncthreads();
    float acc = b2[i];
    #pragma unroll
    for (int j = 0; j < 32; ++j) acc += h1[b][j] * W2[i * 32 + j];
    h2out[b * 32 + i] = acc;
}

// ------- w = tanh(h2 @ Wo^T + bo) -> bf16, + per-block |w| partials (f32) --
__global__ __launch_bounds__(256) void genw(
    const float* __restrict__ Wo, const float* __restrict__ bo,
    const float* __restrict__ h2, bf16* __restrict__ wfb,
    float* __restrict__ part)
{
    __shared__ float h2s[256];
    __shared__ float red[256];
    int t = threadIdx.x;
    h2s[t] = h2[t];
    __syncthreads();
    long o = (long)blockIdx.x * 256 + t;
    float absacc[NB];
    #pragma unroll
    for (int b = 0; b < NB; ++b) absacc[b] = 0.f;
    if (o < ODIM) {
        float row[32];
        const float4* wp = (const float4*)(Wo + o * 32);
        #pragma unroll
        for (int q = 0; q < 8; ++q) {
            float4 v = wp[q];
            row[q*4+0] = v.x; row[q*4+1] = v.y; row[q*4+2] = v.z; row[q*4+3] = v.w;
        }
        float bias = bo[o];
        #pragma unroll
        for (int b = 0; b < NB; ++b) {
            float acc = bias;
            #pragma unroll
            for (int k = 0; k < 32; ++k) acc += h2s[b*32+k] * row[k];
            float w = tanhf(acc);
            wfb[(long)b * ODIM + o] = f2b(w);
            absacc[b] = fabsf(w);
        }
    }
    for (int b = 0; b < NB; ++b) {
        red[t] = absacc[b];
        __syncthreads();
        for (int s = 128; s > 0; s >>= 1) {
            if (t < s) red[t] += red[t + s];
            __syncthreads();
        }
        if (t == 0) part[(long)blockIdx.x * NB + b] = red[0];
        __syncthreads();
    }
}

__global__ __launch_bounds__(256) void l1_reduce(
    const float* __restrict__ part, int nblk, float* __restrict__ outp)
{
    __shared__ float red[256];
    int t = threadIdx.x; int b = t & 7, ch = t >> 3;
    float s = 0.f;
    for (int i = ch; i < nblk; i += 32) s += part[(long)i * 8 + b];
    red[t] = s;
    __syncthreads();
    for (int st = 128; st >= 8; st >>= 1) {
        if (t < st) red[t] += red[t + st];
        __syncthreads();
    }
    if (t < 8) outp[t] = red[t];
}

// ---- repack weights into per-lane MFMA fragment order -------------------
// Layout: frag fid = ((pass*9 + tap)*4 + k4)*2 + oc_half ; then [lane][8].
// Element (fid, lane, j) = W[oc = h*32+(lane&31)]
//                           [ic_full = pass*64 + k4*16 + (lane>>5)*8 + j][tap]
__global__ __launch_bounds__(256) void repack(
    const bf16* __restrict__ wfb, bf16* __restrict__ wr,
    int koff, int Cinfull, long roff, int K)
{
    int i = blockIdx.x * 256 + threadIdx.x;
    int b = blockIdx.y;
    if (i >= 64 * K) return;
    int fid = i >> 9;
    int lane = (i >> 3) & 63;
    int j = i & 7;
    int h = fid & 1;
    int kk = fid >> 1;
    int k4 = kk & 3;
    int tapq = kk >> 2;
    int tap = tapq % 9;
    int pass = tapq / 9;
    int oc = h * 32 + (lane & 31);
    int icf = pass * 64 + k4 * 16 + (lane >> 5) * 8 + j;
    wr[(long)b * WRB + roff + i] =
        wfb[(long)b * ODIM + koff + ((long)oc * Cinfull + icf) * 9 + tap];
}

// ---------------- LDS staging: PLAIN(0) / POOL(1) / UP2(2) ----------------
template<int TR, int TC, int MODE>
__device__ __forceinline__ void stage_tile(
    const bf16* __restrict__ src, int Hc, int Wc, int y0, int x0,
    bf16* lin, int t)
{
    const int XL = TC + 2;
    const int total = (TR + 2) * XL * 8;
    for (int idx = t; idx < total; idx += 256) {
        const int g = idx & 7;
        const int rem = idx >> 3;
        const int xl = rem % XL;
        const int gy = y0 + rem / XL - 1, gx = x0 + xl - 1;
        bf16x8 v = bzero();
        if ((unsigned)gy < (unsigned)Hc && (unsigned)gx < (unsigned)Wc) {
            if constexpr (MODE == 0) {
                v = *(const bf16x8*)(src + (((long)gy * Wc) + gx) * 64 + g * 8);
            } else if constexpr (MODE == 1) {
                const int Ws = Wc * 2;
                const bf16* p = src + (((long)(gy*2) * Ws) + gx*2) * 64 + g * 8;
                bf16x8 aa = *(const bf16x8*)p;
                bf16x8 bb = *(const bf16x8*)(p + 64);
                bf16x8 cc = *(const bf16x8*)(p + (long)Ws * 64);
                bf16x8 dd = *(const bf16x8*)(p + (long)Ws * 64 + 64);
                #pragma unroll
                for (int j = 0; j < 8; ++j) {
                    float m = fmaxf(fmaxf((float)aa[j], (float)bb[j]),
                                    fmaxf((float)cc[j], (float)dd[j]));
                    v[j] = (__bf16)m;
                }
            } else {
                const int Hs = Hc >> 1, Ws = Wc >> 1;
                const float sy = (float)(Hs - 1) / (float)(Hc - 1);
                const float sx = (float)(Ws - 1) / (float)(Wc - 1);
                float ys = gy * sy, xs = gx * sx;
                int yy0 = (int)ys, xx0 = (int)xs;
                int yy1 = min(yy0 + 1, Hs - 1), xx1 = min(xx0 + 1, Ws - 1);
                float wy = ys - (float)yy0, wx = xs - (float)xx0;
                bf16x8 q00 = *(const bf16x8*)(src + ((long)yy0*Ws + xx0)*64 + g*8);
                bf16x8 q01 = *(const bf16x8*)(src + ((long)yy0*Ws + xx1)*64 + g*8);
                bf16x8 q10 = *(const bf16x8*)(src + ((long)yy1*Ws + xx0)*64 + g*8);
                bf16x8 q11 = *(const bf16x8*)(src + ((long)yy1*Ws + xx1)*64 + g*8);
                #pragma unroll
                for (int j = 0; j < 8; ++j) {
                    float r0 = (float)q00[j]*(1.f-wx) + (float)q01[j]*wx;
                    float r1 = (float)q10[j]*(1.f-wx) + (float)q11[j]*wx;
                    v[j] = (__bf16)(r0*(1.f-wy) + r1*wy);
                }
            }
        }
        long byte = (((long)rem) * 128 + g * 16) ^ ((xl & 7) << 4);
        *(bf16x8*)((char*)lin + byte) = v;
    }
}

// ---------------- MFMA implicit-GEMM 3x3 conv, 64 oc, NHWC bf16 -----------
// Block: 64 oc x (TR*TC = 128) pixels. 4 waves; wave = TC-px row-subtile, 2 oc-halves.
// Weights in fragment order -> every A-load is a coalesced 1KB wave-load.
template<int TR, int TC, int MODE>
__global__ __launch_bounds__(256, 4) void conv_mfma(
    const bf16* __restrict__ src1, const bf16* __restrict__ src2,
    int Hc, int Wc,
    const bf16* __restrict__ wr, long roff,
    const bf16* __restrict__ wfb, int boff,
    bf16* __restrict__ outp)
{
    const int XL = TC + 2;
    __shared__ bf16 lin[(TR + 2) * (TC + 2) * 64];
    const int t = threadIdx.x;
    const int lane = t & 63;
    const int w = t >> 6;
    const int b = blockIdx.z;
    const int y0 = blockIdx.y * TR;
    const int x0 = blockIdx.x * TC;

    const int nx = TC / 32;
    const int rw = w / nx;
    const int cb = (w % nx) * 32;
    const int lx = cb + (lane & 31);

    f32x16 acc0 = {};
    f32x16 acc1 = {};

    const bf16* wl = wr + (long)b * WRB + roff;

    int xl128[3], swz[3];
    #pragma unroll
    for (int d = 0; d < 3; ++d) {
        int xl = lx + d;
        xl128[d] = xl * 128;
        swz[d] = (xl & 7) << 4;
    }
    const int icbl = (lane >> 5) * 16;   // lane k-group byte offset

    auto kpass = [&](int p) {
        #pragma unroll
        for (int tap = 0; tap < 9; ++tap) {
            const int dy = tap / 3, dxi = tap % 3;
            const int rb = (rw + dy) * (XL * 128);
            #pragma unroll
            for (int k4 = 0; k4 < 4; ++k4) {
                const int fid = ((p * 9 + tap) * 4 + k4) * 2;
                const bf16* pk = wl + ((long)fid << 9) + (lane << 3);
                bf16x8 a0 = *(const bf16x8*)pk;
                bf16x8 a1 = *(const bf16x8*)(pk + 512);
                const int icb = k4 * 32 + icbl;
                const int a_ = rb + xl128[dxi] + (icb ^ swz[dxi]);
                bf16x8 bfrag = *(const bf16x8*)((const char*)lin + a_);
                acc0 = __builtin_amdgcn_mfma_f32_32x32x16_bf16(a0, bfrag, acc0, 0, 0, 0);
                acc1 = __builtin_amdgcn_mfma_f32_32x32x16_bf16(a1, bfrag, acc1, 0, 0, 0);
            }
        }
    };

    stage_tile<TR, TC, MODE>(src1, Hc, Wc, y0, x0, lin, t);
    __syncthreads();
    kpass(0);
    if (src2) {
        __syncthreads();
        stage_tile<TR, TC, 0>(src2, Hc, Wc, y0, x0, lin, t);
        __syncthreads();
        kpass(1);
    }

    // ---- epilogue: acc -> LDS [pix][oc] (swizzled) -> coalesced store ----
    __syncthreads();
    const long bb = (long)b * ODIM + boff;
    const int pixidx = rw * TC + lx;
    const int psw = (pixidx & 7) << 4;
    #pragma unroll
    for (int ocs = 0; ocs < 2; ++ocs) {
        const f32x16& A = ocs ? acc1 : acc0;
        #pragma unroll
        for (int q = 0; q < 4; ++q) {
            const int oc0 = ocs * 32 + 8 * q + 4 * (lane >> 5);
            ushort4 pk;
            float v0 = fmaxf(A[4*q+0] + b2f(wfb[bb + oc0 + 0]), 0.f);
            float v1 = fmaxf(A[4*q+1] + b2f(wfb[bb + oc0 + 1]), 0.f);
            float v2 = fmaxf(A[4*q+2] + b2f(wfb[bb + oc0 + 2]), 0.f);
            float v3 = fmaxf(A[4*q+3] + b2f(wfb[bb + oc0 + 3]), 0.f);
            pk.x = __builtin_bit_cast(unsigned short, f2b(v0));
            pk.y = __builtin_bit_cast(unsigned short, f2b(v1));
            pk.z = __builtin_bit_cast(unsigned short, f2b(v2));
            pk.w = __builtin_bit_cast(unsigned short, f2b(v3));
            long byte = ((long)pixidx * 128 + oc0 * 2) ^ psw;
            *(ushort4*)((char*)lin + byte) = pk;
        }
    }
    __syncthreads();
    bf16* outt = outp + (((long)b * Hc + y0) * Wc + x0) * 64;
    #pragma unroll
    for (int off = t * 16; off < TR * TC * 128; off += 4096) {
        int pix = off >> 7;
        int r = pix / TC, c = pix % TC;
        long sb = (long)off ^ ((pix & 7) << 4);
        bf16x8 v = *(const bf16x8*)((const char*)lin + sb);
        *(bf16x8*)((char*)outt + ((long)(r * Wc + c)) * 128 + (off & 127)) = v;
    }
}

// ---------------- conv0: 2->64 @256, zf f32 NHWC direct -------------------
__global__ __launch_bounds__(256) void conv0_k(
    const float* __restrict__ zf, const bf16* __restrict__ wfb,
    bf16* __restrict__ outp)
{
    __shared__ float wsh[2][9][64];
    __shared__ float bsh[64];
    const int t = threadIdx.x;
    const int b = blockIdx.z;
    const long wb = (long)b * ODIM;
    for (int i = t; i < 1152; i += 256) {
        int oc = i / 18, r2 = i % 18, ic = r2 / 9, tap = r2 % 9;
        wsh[ic][tap][oc] = b2f(wfb[wb + i]);
    }
    if (t < 64) bsh[t] = b2f(wfb[wb + 591104 + t]);
    __syncthreads();
    const int pl = t >> 3, g = t & 7;
    const int pix = blockIdx.x * 32 + pl;
    const int y = pix >> 8, x = pix & 255;
    float acc[8];
    #pragma unroll
    for (int j = 0; j < 8; ++j) acc[j] = bsh[g * 8 + j];
    const float* zb = zf + (long)b * 131072;
    #pragma unroll
    for (int dy = 0; dy < 3; ++dy) {
        int yy = y + dy - 1;
        if ((unsigned)yy >= 256u) continue;
        #pragma unroll
        for (int dx = 0; dx < 3; ++dx) {
            int xx = x + dx - 1;
            if ((unsigned)xx >= 256u) continue;
            const float* p = zb + ((long)yy * 256 + xx) * 2;
            float v0 = p[0], v1 = p[1];
            int tap = dy * 3 + dx;
            #pragma unroll
            for (int j = 0; j < 8; ++j)
                acc[j] += v0 * wsh[0][tap][g*8+j] + v1 * wsh[1][tap][g*8+j];
        }
    }
    bf16x8 v;
    #pragma unroll
    for (int j = 0; j < 8; ++j) v[j] = (__bf16)fmaxf(acc[j], 0.f);
    *(bf16x8*)(outp + ((long)b * 65536 + pix) * 64 + g * 8) = v;
}

// ---------- final 1x1 conv (64->2) + residual + NHWC f32 store ------------
__global__ __launch_bounds__(256) void final_k(
    const bf16* __restrict__ X, const bf16* __restrict__ wfb,
    const float* __restrict__ zf, float* __restrict__ outp)
{
    __shared__ float wsh[128];
    __shared__ float bsh[2];
    const int t = threadIdx.x;
    const int i = blockIdx.x * 256 + t;
    const int pix = i & 65535;
    const int b = i >> 16;
    const long wb = (long)b * ODIM;
    if (t < 128) wsh[t] = b2f(wfb[wb + 590976 + t]);
    if (t < 2) bsh[t] = b2f(wfb[wb + 592000 + t]);
    __syncthreads();
    const bf16* p = X + ((long)b * 65536 + pix) * 64;
    float a0 = bsh[0], a1 = bsh[1];
    #pragma unroll
    for (int gq = 0; gq < 8; ++gq) {
        bf16x8 v = *(const bf16x8*)(p + gq * 8);
        #pragma unroll
        for (int j = 0; j < 8; ++j) {
            float f = (float)v[j];
            a0 += f * wsh[gq*8 + j];
            a1 += f * wsh[64 + gq*8 + j];
        }
    }
    long zi = ((long)b * 65536 + pix) * 2;
    outp[zi] = zf[zi] + a0;
    outp[zi + 1] = zf[zi + 1] + a1;
}

extern "C" void kernel_launch(void* const* d_in, const int* in_sizes, int n_in,
                              void* d_out, int out_size, void* d_ws, size_t ws_size,
                              hipStream_t stream)
{
    (void)in_sizes; (void)n_in; (void)out_size; (void)ws_size;
    const float* zf = (const float*)d_in[0];
    const float* hp = (const float*)d_in[2];
    const float* W1 = (const float*)d_in[3];
    const float* b1 = (const float*)d_in[4];
    const float* W2 = (const float*)d_in[5];
    const float* b2 = (const float*)d_in[6];
    const float* Wo = (const float*)d_in[7];
    const float* bo = (const float*)d_in[8];
    float* out = (float*)d_out;

    // ---- workspace carve (~218 MB) ----
    char* base = (char*)d_ws;
    float* h2   = (float*)base;  base += 1024;
    float* part = (float*)base;  base += 18504L * 4 + 32;
    bf16* wfb   = (bf16*)base;   base += 4736016L * 2 + 32;   // tanh weights (flat)
    bf16* WREP  = (bf16*)base;   base += 4718592L * 2;        // fragment-ordered weights
    bf16* Y256  = (bf16*)base;   base += 33554432L * 2;       // 8*256*256*64
    bf16* C1s   = (bf16*)base;   base += 33554432L * 2;
    bf16* D128a = (bf16*)base;   base += 8388608L * 2;        // 8*128*128*64
    bf16* C2s   = (bf16*)base;   base += 8388608L * 2;
    bf16* X128  = (bf16*)base;   base += 8388608L * 2;
    bf16* E64a  = (bf16*)base;   base += 2097152L * 2;        // 8*64*64*64
    bf16* C3s   = (bf16*)base;   base += 2097152L * 2;
    bf16* X64   = (bf16*)base;   base += 2097152L * 2;
    bf16* F32a  = (bf16*)base;   base += 524288L * 2;         // 8*32*32*64
    bf16* C4    = (bf16*)base;   base += 524288L * 2;

    hyper_h<<<1, 256, 0, stream>>>(hp, W1, b1, W2, b2, h2);
    const int ngb = (int)((ODIM + 255) / 256);   // 2313
    genw<<<ngb, 256, 0, stream>>>(Wo, bo, h2, wfb, part);
    l1_reduce<<<1, 256, 0, stream>>>(part, ngb, out + 1048576);

    // flat kernel offsets in wfb
    const int K1=1152, K2=38016, K3=74880, K4=111744, K5=148608,
              K6=185472, K7=222336, K8=259200, K9=332928, K10=369792,
              K11=443520, K12=480384, K13=554112;
    const int BB = 591104;
    // repacked offsets (element counts unchanged)
    const long R1=0, R2=36864, R3=73728, R4=110592, R5=147456, R6=184320,
               R7=221184, R8=258048, R9=331776, R10=368640, R11=442368,
               R12=479232, R13=552960;

    repack<<<dim3(144, 8), 256, 0, stream>>>(wfb, WREP, K1, 64, R1, 576);
    repack<<<dim3(144, 8), 256, 0, stream>>>(wfb, WREP, K2, 64, R2, 576);
    repack<<<dim3(144, 8), 256, 0, stream>>>(wfb, WREP, K3, 64, R3, 576);
    repack<<<dim3(144, 8), 256, 0, stream>>>(wfb, WREP, K4, 64, R4, 576);
    repack<<<dim3(144, 8), 256, 0, stream>>>(wfb, WREP, K5, 64, R5, 576);
    repack<<<dim3(144, 8), 256, 0, stream>>>(wfb, WREP, K6, 64, R6, 576);
    repack<<<dim3(144, 8), 256, 0, stream>>>(wfb, WREP, K7, 64, R7, 576);
    repack<<<dim3(288, 8), 256, 0, stream>>>(wfb, WREP, K8, 128, R8, 1152);
    repack<<<dim3(144, 8), 256, 0, stream>>>(wfb, WREP, K9, 64, R9, 576);
    repack<<<dim3(288, 8), 256, 0, stream>>>(wfb, WREP, K10, 128, R10, 1152);
    repack<<<dim3(144, 8), 256, 0, stream>>>(wfb, WREP, K11, 64, R11, 576);
    repack<<<dim3(288, 8), 256, 0, stream>>>(wfb, WREP, K12, 128, R12, 1152);
    repack<<<dim3(144, 8), 256, 0, stream>>>(wfb, WREP, K13, 64, R13, 576);

    conv0_k<<<dim3(2048, 1, 8), 256, 0, stream>>>(zf, wfb, Y256);

    // encoder  (tiles: TR=4, TC=32 -> 128 px/block, 26KB LDS)
    conv_mfma<4,32,0><<<dim3(8,64,8),  256, 0, stream>>>(Y256, nullptr, 256,256, WREP, R1,  wfb, BB+64,  C1s);
    conv_mfma<4,32,1><<<dim3(4,32,8),  256, 0, stream>>>(C1s,  nullptr, 128,128, WREP, R2,  wfb, BB+128, D128a);
    conv_mfma<4,32,0><<<dim3(4,32,8),  256, 0, stream>>>(D128a,nullptr, 128,128, WREP, R3,  wfb, BB+192, C2s);
    conv_mfma<4,32,1><<<dim3(2,16,8),  256, 0, stream>>>(C2s,  nullptr, 64,64,   WREP, R4,  wfb, BB+256, E64a);
    conv_mfma<4,32,0><<<dim3(2,16,8),  256, 0, stream>>>(E64a, nullptr, 64,64,   WREP, R5,  wfb, BB+320, C3s);
    conv_mfma<4,32,1><<<dim3(1,8,8),   256, 0, stream>>>(C3s,  nullptr, 32,32,   WREP, R6,  wfb, BB+384, F32a);
    conv_mfma<4,32,0><<<dim3(1,8,8),   256, 0, stream>>>(F32a, nullptr, 32,32,   WREP, R7,  wfb, BB+448, C4);
    // decoder (UP fused into staging; concat = 2nd K-pass)
    conv_mfma<4,32,2><<<dim3(2,16,8),  256, 0, stream>>>(C4,   C3s, 64,64,   WREP, R8,  wfb, BB+512, E64a);
    conv_mfma<4,32,0><<<dim3(2,16,8),  256, 0, stream>>>(E64a, nullptr, 64,64, WREP, R9,  wfb, BB+576, X64);
    conv_mfma<4,32,2><<<dim3(4,32,8),  256, 0, stream>>>(X64,  C2s, 128,128, WREP, R10, wfb, BB+640, D128a);
    conv_mfma<4,32,0><<<dim3(4,32,8),  256, 0, stream>>>(D128a,nullptr,128,128, WREP, R11, wfb, BB+704, X128);
    conv_mfma<4,32,2><<<dim3(8,64,8),  256, 0, stream>>>(X128, C1s, 256,256, WREP, R12, wfb, BB+768, Y256);
    conv_mfma<4,32,0><<<dim3(8,64,8),  256, 0, stream>>>(Y256, nullptr,256,256, WREP, R13, wfb, BB+832, C1s);

    final_k<<<dim3(2048), 256, 0, stream>>>(C1s, wfb, zf, out);
}

// Round 5
// 629.677 us; speedup vs baseline: 16.6988x; 1.2537x over previous
//
#include <hip/hip_runtime.h>
#include <hip/hip_bf16.h>
#include <math.h>

#define ODIM 592002L
#define WRB  589824L
#define NB 8

typedef __hip_bfloat16 bf16;
typedef __bf16  bf16x8 __attribute__((ext_vector_type(8)));
typedef float   f32x16 __attribute__((ext_vector_type(16)));
typedef short   s16x8  __attribute__((ext_vector_type(8)));

__device__ __forceinline__ float b2f(bf16 x) { return __bfloat162float(x); }
__device__ __forceinline__ bf16 f2b(float x) { return __float2bfloat16(x); }
__device__ __forceinline__ bf16x8 bzero() { return __builtin_bit_cast(bf16x8, (s16x8)0); }

// ---------------- hypernet: h2 = (hp*W1^T + b1) @ W2^T + b2 ----------------
__global__ __launch_bounds__(256) void hyper_h(
    const float* __restrict__ hp, const float* __restrict__ W1,
    const float* __restrict__ b1, const float* __restrict__ W2,
    const float* __restrict__ b2, float* __restrict__ h2out)
{
    __shared__ float h1[NB][32];
    int t = threadIdx.x;
    int b = t >> 5, i = t & 31;
    h1[b][i] = hp[b] * W1[i] + b1[i];
    __syncthreads();
    float acc = b2[i];
    #pragma unroll
    for (int j = 0; j < 32; ++j) acc += h1[b][j] * W2[i * 32 + j];
    h2out[b * 32 + i] = acc;
}

// ------- w = tanh(h2 @ Wo^T + bo) -> bf16, + per-block |w| partials (f32) --
__global__ __launch_bounds__(256) void genw(
    const float* __restrict__ Wo, const float* __restrict__ bo,
    const float* __restrict__ h2, bf16* __restrict__ wfb,
    float* __restrict__ part)
{
    __shared__ float h2s[256];
    __shared__ float red[256];
    int t = threadIdx.x;
    h2s[t] = h2[t];
    __syncthreads();
    long o = (long)blockIdx.x * 256 + t;
    float absacc[NB];
    #pragma unroll
    for (int b = 0; b < NB; ++b) absacc[b] = 0.f;
    if (o < ODIM) {
        float row[32];
        const float4* wp = (const float4*)(Wo + o * 32);
        #pragma unroll
        for (int q = 0; q < 8; ++q) {
            float4 v = wp[q];
            row[q*4+0] = v.x; row[q*4+1] = v.y; row[q*4+2] = v.z; row[q*4+3] = v.w;
        }
        float bias = bo[o];
        #pragma unroll
        for (int b = 0; b < NB; ++b) {
            float acc = bias;
            #pragma unroll
            for (int k = 0; k < 32; ++k) acc += h2s[b*32+k] * row[k];
            float w = tanhf(acc);
            wfb[(long)b * ODIM + o] = f2b(w);
            absacc[b] = fabsf(w);
        }
    }
    for (int b = 0; b < NB; ++b) {
        red[t] = absacc[b];
        __syncthreads();
        for (int s = 128; s > 0; s >>= 1) {
            if (t < s) red[t] += red[t + s];
            __syncthreads();
        }
        if (t == 0) part[(long)blockIdx.x * NB + b] = red[0];
        __syncthreads();
    }
}

__global__ __launch_bounds__(256) void l1_reduce(
    const float* __restrict__ part, int nblk, float* __restrict__ outp)
{
    __shared__ float red[256];
    int t = threadIdx.x; int b = t & 7, ch = t >> 3;
    float s = 0.f;
    for (int i = ch; i < nblk; i += 32) s += part[(long)i * 8 + b];
    red[t] = s;
    __syncthreads();
    for (int st = 128; st >= 8; st >>= 1) {
        if (t < st) red[t] += red[t + st];
        __syncthreads();
    }
    if (t < 8) outp[t] = red[t];
}

// ---- repack weights into per-lane MFMA fragment order -------------------
// frag fid = ((pass*9 + tap)*4 + k4)*2 + oc_half ; then [lane][8].
__global__ __launch_bounds__(256) void repack(
    const bf16* __restrict__ wfb, bf16* __restrict__ wr,
    int koff, int Cinfull, long roff, int K)
{
    int i = blockIdx.x * 256 + threadIdx.x;
    int b = blockIdx.y;
    if (i >= 64 * K) return;
    int fid = i >> 9;
    int lane = (i >> 3) & 63;
    int j = i & 7;
    int h = fid & 1;
    int kk = fid >> 1;
    int k4 = kk & 3;
    int tapq = kk >> 2;
    int tap = tapq % 9;
    int pass = tapq / 9;
    int oc = h * 32 + (lane & 31);
    int icf = pass * 64 + k4 * 16 + (lane >> 5) * 8 + j;
    wr[(long)b * WRB + roff + i] =
        wfb[(long)b * ODIM + koff + ((long)oc * Cinfull + icf) * 9 + tap];
}

// ---------------- LDS staging: PLAIN(0) / POOL(1) / UP2(2) ----------------
template<int TR, int TC, int MODE>
__device__ __forceinline__ void stage_tile(
    const bf16* __restrict__ src, int Hc, int Wc, int y0, int x0,
    bf16* lin, int t)
{
    const int XL = TC + 2;
    const int total = (TR + 2) * XL * 8;
    for (int idx = t; idx < total; idx += 256) {
        const int g = idx & 7;
        const int rem = idx >> 3;
        const int xl = rem % XL;
        const int gy = y0 + rem / XL - 1, gx = x0 + xl - 1;
        bf16x8 v = bzero();
        if ((unsigned)gy < (unsigned)Hc && (unsigned)gx < (unsigned)Wc) {
            if constexpr (MODE == 0) {
                v = *(const bf16x8*)(src + (((long)gy * Wc) + gx) * 64 + g * 8);
            } else if constexpr (MODE == 1) {
                const int Ws = Wc * 2;
                const bf16* p = src + (((long)(gy*2) * Ws) + gx*2) * 64 + g * 8;
                bf16x8 aa = *(const bf16x8*)p;
                bf16x8 bb = *(const bf16x8*)(p + 64);
                bf16x8 cc = *(const bf16x8*)(p + (long)Ws * 64);
                bf16x8 dd = *(const bf16x8*)(p + (long)Ws * 64 + 64);
                #pragma unroll
                for (int j = 0; j < 8; ++j) {
                    float m = fmaxf(fmaxf((float)aa[j], (float)bb[j]),
                                    fmaxf((float)cc[j], (float)dd[j]));
                    v[j] = (__bf16)m;
                }
            } else {
                const int Hs = Hc >> 1, Ws = Wc >> 1;
                const float sy = (float)(Hs - 1) / (float)(Hc - 1);
                const float sx = (float)(Ws - 1) / (float)(Wc - 1);
                float ys = gy * sy, xs = gx * sx;
                int yy0 = (int)ys, xx0 = (int)xs;
                int yy1 = min(yy0 + 1, Hs - 1), xx1 = min(xx0 + 1, Ws - 1);
                float wy = ys - (float)yy0, wx = xs - (float)xx0;
                bf16x8 q00 = *(const bf16x8*)(src + ((long)yy0*Ws + xx0)*64 + g*8);
                bf16x8 q01 = *(const bf16x8*)(src + ((long)yy0*Ws + xx1)*64 + g*8);
                bf16x8 q10 = *(const bf16x8*)(src + ((long)yy1*Ws + xx0)*64 + g*8);
                bf16x8 q11 = *(const bf16x8*)(src + ((long)yy1*Ws + xx1)*64 + g*8);
                #pragma unroll
                for (int j = 0; j < 8; ++j) {
                    float r0 = (float)q00[j]*(1.f-wx) + (float)q01[j]*wx;
                    float r1 = (float)q10[j]*(1.f-wx) + (float)q11[j]*wx;
                    v[j] = (__bf16)(r0*(1.f-wy) + r1*wy);
                }
            }
        }
        long byte = (((long)rem) * 128 + g * 16) ^ ((xl & 7) << 4);
        *(bf16x8*)((char*)lin + byte) = v;
    }
}

// ---------------- MFMA implicit-GEMM 3x3 conv, 64 oc, NHWC bf16 -----------
// Tile TR=8 x TC=32 = 256 px. 4 waves; wave owns rows {w, w+4} x 2 oc-halves
// (4 acc chains). Per tap: 8 weight frags preloaded to regs, then 4 k-steps
// x 4 MFMA. Weights in fragment order -> coalesced 1KB wave-loads.
template<int MODE>
__global__ __launch_bounds__(256, 3) void conv_mfma(
    const bf16* __restrict__ src1, const bf16* __restrict__ src2,
    int Hc, int Wc,
    const bf16* __restrict__ wr, long roff,
    const bf16* __restrict__ wfb, int boff,
    bf16* __restrict__ outp)
{
    const int TR = 8, TC = 32, XL = TC + 2;
    __shared__ bf16 lin[(TR + 2) * XL * 64];
    __shared__ float biasf[64];
    const int t = threadIdx.x;
    const int lane = t & 63;
    const int w = t >> 6;
    const int b = blockIdx.z;
    const int y0 = blockIdx.y * TR;
    const int x0 = blockIdx.x * TC;
    const int lx = lane & 31;

    f32x16 acc00 = {}, acc01 = {}, acc10 = {}, acc11 = {};

    const bf16* wl = wr + (long)b * WRB + roff;
    const long bb = (long)b * ODIM + boff;
    if (t < 64) biasf[t] = b2f(wfb[bb + t]);

    int xl128[3], swz[3];
    #pragma unroll
    for (int d = 0; d < 3; ++d) {
        int xl = lx + d;
        xl128[d] = xl * 128;
        swz[d] = (xl & 7) << 4;
    }
    const int icbl = (lane >> 5) * 16;

    auto kpass = [&](int p) {
        #pragma unroll
        for (int tap = 0; tap < 9; ++tap) {
            const int dy = tap / 3, dxi = tap % 3;
            const int rb0 = (w + dy) * (XL * 128);
            const int rb1 = (w + 4 + dy) * (XL * 128);
            bf16x8 af[4][2];
            #pragma unroll
            for (int k4 = 0; k4 < 4; ++k4) {
                const int fid = ((p * 9 + tap) * 4 + k4) * 2;
                const bf16* pk = wl + ((long)fid << 9) + (lane << 3);
                af[k4][0] = *(const bf16x8*)pk;
                af[k4][1] = *(const bf16x8*)(pk + 512);
            }
            #pragma unroll
            for (int k4 = 0; k4 < 4; ++k4) {
                const int co = xl128[dxi] + ((k4 * 32 + icbl) ^ swz[dxi]);
                bf16x8 b0 = *(const bf16x8*)((const char*)lin + rb0 + co);
                bf16x8 b1 = *(const bf16x8*)((const char*)lin + rb1 + co);
                acc00 = __builtin_amdgcn_mfma_f32_32x32x16_bf16(af[k4][0], b0, acc00, 0, 0, 0);
                acc01 = __builtin_amdgcn_mfma_f32_32x32x16_bf16(af[k4][1], b0, acc01, 0, 0, 0);
                acc10 = __builtin_amdgcn_mfma_f32_32x32x16_bf16(af[k4][0], b1, acc10, 0, 0, 0);
                acc11 = __builtin_amdgcn_mfma_f32_32x32x16_bf16(af[k4][1], b1, acc11, 0, 0, 0);
            }
        }
    };

    stage_tile<TR, TC, MODE>(src1, Hc, Wc, y0, x0, lin, t);
    __syncthreads();
    kpass(0);
    if (src2) {
        __syncthreads();
        stage_tile<TR, TC, 0>(src2, Hc, Wc, y0, x0, lin, t);
        __syncthreads();
        kpass(1);
    }

    // ---- epilogue: acc -> LDS [pix][oc] (swizzled) -> coalesced store ----
    __syncthreads();
    #pragma unroll
    for (int half = 0; half < 2; ++half) {
        const int r = w + half * 4;
        const int pixidx = r * TC + lx;
        const int psw = (pixidx & 7) << 4;
        #pragma unroll
        for (int ocs = 0; ocs < 2; ++ocs) {
            const f32x16& A = half ? (ocs ? acc11 : acc10) : (ocs ? acc01 : acc00);
            #pragma unroll
            for (int q = 0; q < 4; ++q) {
                const int oc0 = ocs * 32 + 8 * q + 4 * (lane >> 5);
                ushort4 pk;
                float v0 = fmaxf(A[4*q+0] + biasf[oc0 + 0], 0.f);
                float v1 = fmaxf(A[4*q+1] + biasf[oc0 + 1], 0.f);
                float v2 = fmaxf(A[4*q+2] + biasf[oc0 + 2], 0.f);
                float v3 = fmaxf(A[4*q+3] + biasf[oc0 + 3], 0.f);
                pk.x = __builtin_bit_cast(unsigned short, f2b(v0));
                pk.y = __builtin_bit_cast(unsigned short, f2b(v1));
                pk.z = __builtin_bit_cast(unsigned short, f2b(v2));
                pk.w = __builtin_bit_cast(unsigned short, f2b(v3));
                long byte = ((long)pixidx * 128 + oc0 * 2) ^ psw;
                *(ushort4*)((char*)lin + byte) = pk;
            }
        }
    }
    __syncthreads();
    bf16* outt = outp + (((long)b * Hc + y0) * Wc + x0) * 64;
    #pragma unroll
    for (int off = t * 16; off < TR * TC * 128; off += 4096) {
        int pix = off >> 7;
        int r = pix >> 5, c = pix & 31;
        long sb = (long)off ^ ((pix & 7) << 4);
        bf16x8 v = *(const bf16x8*)((const char*)lin + sb);
        *(bf16x8*)((char*)outt + ((long)(r * Wc + c)) * 128 + (off & 127)) = v;
    }
}

// ---------------- conv0: 2->64 @256, zf f32 NHWC direct -------------------
__global__ __launch_bounds__(256) void conv0_k(
    const float* __restrict__ zf, const bf16* __restrict__ wfb,
    bf16* __restrict__ outp)
{
    __shared__ float wsh[2][9][64];
    __shared__ float bsh[64];
    const int t = threadIdx.x;
    const int b = blockIdx.z;
    const long wb = (long)b * ODIM;
    for (int i = t; i < 1152; i += 256) {
        int oc = i / 18, r2 = i % 18, ic = r2 / 9, tap = r2 % 9;
        wsh[ic][tap][oc] = b2f(wfb[wb + i]);
    }
    if (t < 64) bsh[t] = b2f(wfb[wb + 591104 + t]);
    __syncthreads();
    const int pl = t >> 3, g = t & 7;
    const int pix = blockIdx.x * 32 + pl;
    const int y = pix >> 8, x = pix & 255;
    float acc[8];
    #pragma unroll
    for (int j = 0; j < 8; ++j) acc[j] = bsh[g * 8 + j];
    const float* zb = zf + (long)b * 131072;
    #pragma unroll
    for (int dy = 0; dy < 3; ++dy) {
        int yy = y + dy - 1;
        if ((unsigned)yy >= 256u) continue;
        #pragma unroll
        for (int dx = 0; dx < 3; ++dx) {
            int xx = x + dx - 1;
            if ((unsigned)xx >= 256u) continue;
            const float* p = zb + ((long)yy * 256 + xx) * 2;
            float v0 = p[0], v1 = p[1];
            int tap = dy * 3 + dx;
            #pragma unroll
            for (int j = 0; j < 8; ++j)
                acc[j] += v0 * wsh[0][tap][g*8+j] + v1 * wsh[1][tap][g*8+j];
        }
    }
    bf16x8 v;
    #pragma unroll
    for (int j = 0; j < 8; ++j) v[j] = (__bf16)fmaxf(acc[j], 0.f);
    *(bf16x8*)(outp + ((long)b * 65536 + pix) * 64 + g * 8) = v;
}

// ---------- final 1x1 conv (64->2) + residual + NHWC f32 store ------------
__global__ __launch_bounds__(256) void final_k(
    const bf16* __restrict__ X, const bf16* __restrict__ wfb,
    const float* __restrict__ zf, float* __restrict__ outp)
{
    __shared__ float wsh[128];
    __shared__ float bsh[2];
    const int t = threadIdx.x;
    const int i = blockIdx.x * 256 + t;
    const int pix = i & 65535;
    const int b = i >> 16;
    const long wb = (long)b * ODIM;
    if (t < 128) wsh[t] = b2f(wfb[wb + 590976 + t]);
    if (t < 2) bsh[t] = b2f(wfb[wb + 592000 + t]);
    __syncthreads();
    const bf16* p = X + ((long)b * 65536 + pix) * 64;
    float a0 = bsh[0], a1 = bsh[1];
    #pragma unroll
    for (int gq = 0; gq < 8; ++gq) {
        bf16x8 v = *(const bf16x8*)(p + gq * 8);
        #pragma unroll
        for (int j = 0; j < 8; ++j) {
            float f = (float)v[j];
            a0 += f * wsh[gq*8 + j];
            a1 += f * wsh[64 + gq*8 + j];
        }
    }
    long zi = ((long)b * 65536 + pix) * 2;
    outp[zi] = zf[zi] + a0;
    outp[zi + 1] = zf[zi + 1] + a1;
}

extern "C" void kernel_launch(void* const* d_in, const int* in_sizes, int n_in,
                              void* d_out, int out_size, void* d_ws, size_t ws_size,
                              hipStream_t stream)
{
    (void)in_sizes; (void)n_in; (void)out_size; (void)ws_size;
    const float* zf = (const float*)d_in[0];
    const float* hp = (const float*)d_in[2];
    const float* W1 = (const float*)d_in[3];
    const float* b1 = (const float*)d_in[4];
    const float* W2 = (const float*)d_in[5];
    const float* b2 = (const float*)d_in[6];
    const float* Wo = (const float*)d_in[7];
    const float* bo = (const float*)d_in[8];
    float* out = (float*)d_out;

    // ---- workspace carve (~218 MB) ----
    char* base = (char*)d_ws;
    float* h2   = (float*)base;  base += 1024;
    float* part = (float*)base;  base += 18504L * 4 + 32;
    bf16* wfb   = (bf16*)base;   base += 4736016L * 2 + 32;   // tanh weights (flat)
    bf16* WREP  = (bf16*)base;   base += 4718592L * 2;        // fragment-ordered weights
    bf16* Y256  = (bf16*)base;   base += 33554432L * 2;       // 8*256*256*64
    bf16* C1s   = (bf16*)base;   base += 33554432L * 2;
    bf16* D128a = (bf16*)base;   base += 8388608L * 2;        // 8*128*128*64
    bf16* C2s   = (bf16*)base;   base += 8388608L * 2;
    bf16* X128  = (bf16*)base;   base += 8388608L * 2;
    bf16* E64a  = (bf16*)base;   base += 2097152L * 2;        // 8*64*64*64
    bf16* C3s   = (bf16*)base;   base += 2097152L * 2;
    bf16* X64   = (bf16*)base;   base += 2097152L * 2;
    bf16* F32a  = (bf16*)base;   base += 524288L * 2;         // 8*32*32*64
    bf16* C4    = (bf16*)base;   base += 524288L * 2;

    hyper_h<<<1, 256, 0, stream>>>(hp, W1, b1, W2, b2, h2);
    const int ngb = (int)((ODIM + 255) / 256);   // 2313
    genw<<<ngb, 256, 0, stream>>>(Wo, bo, h2, wfb, part);
    l1_reduce<<<1, 256, 0, stream>>>(part, ngb, out + 1048576);

    // flat kernel offsets in wfb
    const int K1=1152, K2=38016, K3=74880, K4=111744, K5=148608,
              K6=185472, K7=222336, K8=259200, K9=332928, K10=369792,
              K11=443520, K12=480384, K13=554112;
    const int BB = 591104;
    // repacked offsets
    const long R1=0, R2=36864, R3=73728, R4=110592, R5=147456, R6=184320,
               R7=221184, R8=258048, R9=331776, R10=368640, R11=442368,
               R12=479232, R13=552960;

    repack<<<dim3(144, 8), 256, 0, stream>>>(wfb, WREP, K1, 64, R1, 576);
    repack<<<dim3(144, 8), 256, 0, stream>>>(wfb, WREP, K2, 64, R2, 576);
    repack<<<dim3(144, 8), 256, 0, stream>>>(wfb, WREP, K3, 64, R3, 576);
    repack<<<dim3(144, 8), 256, 0, stream>>>(wfb, WREP, K4, 64, R4, 576);
    repack<<<dim3(144, 8), 256, 0, stream>>>(wfb, WREP, K5, 64, R5, 576);
    repack<<<dim3(144, 8), 256, 0, stream>>>(wfb, WREP, K6, 64, R6, 576);
    repack<<<dim3(144, 8), 256, 0, stream>>>(wfb, WREP, K7, 64, R7, 576);
    repack<<<dim3(288, 8), 256, 0, stream>>>(wfb, WREP, K8, 128, R8, 1152);
    repack<<<dim3(144, 8), 256, 0, stream>>>(wfb, WREP, K9, 64, R9, 576);
    repack<<<dim3(288, 8), 256, 0, stream>>>(wfb, WREP, K10, 128, R10, 1152);
    repack<<<dim3(144, 8), 256, 0, stream>>>(wfb, WREP, K11, 64, R11, 576);
    repack<<<dim3(288, 8), 256, 0, stream>>>(wfb, WREP, K12, 128, R12, 1152);
    repack<<<dim3(144, 8), 256, 0, stream>>>(wfb, WREP, K13, 64, R13, 576);

    conv0_k<<<dim3(2048, 1, 8), 256, 0, stream>>>(zf, wfb, Y256);

    // encoder  (tile: TR=8, TC=32 -> 256 px/block, 43.5KB LDS)
    conv_mfma<0><<<dim3(8,32,8),  256, 0, stream>>>(Y256, nullptr, 256,256, WREP, R1,  wfb, BB+64,  C1s);
    conv_mfma<1><<<dim3(4,16,8),  256, 0, stream>>>(C1s,  nullptr, 128,128, WREP, R2,  wfb, BB+128, D128a);
    conv_mfma<0><<<dim3(4,16,8),  256, 0, stream>>>(D128a,nullptr, 128,128, WREP, R3,  wfb, BB+192, C2s);
    conv_mfma<1><<<dim3(2,8,8),   256, 0, stream>>>(C2s,  nullptr, 64,64,   WREP, R4,  wfb, BB+256, E64a);
    conv_mfma<0><<<dim3(2,8,8),   256, 0, stream>>>(E64a, nullptr, 64,64,   WREP, R5,  wfb, BB+320, C3s);
    conv_mfma<1><<<dim3(1,4,8),   256, 0, stream>>>(C3s,  nullptr, 32,32,   WREP, R6,  wfb, BB+384, F32a);
    conv_mfma<0><<<dim3(1,4,8),   256, 0, stream>>>(F32a, nullptr, 32,32,   WREP, R7,  wfb, BB+448, C4);
    // decoder (UP fused into staging; concat = 2nd K-pass)
    conv_mfma<2><<<dim3(2,8,8),   256, 0, stream>>>(C4,   C3s, 64,64,   WREP, R8,  wfb, BB+512, E64a);
    conv_mfma<0><<<dim3(2,8,8),   256, 0, stream>>>(E64a, nullptr, 64,64, WREP, R9,  wfb, BB+576, X64);
    conv_mfma<2><<<dim3(4,16,8),  256, 0, stream>>>(X64,  C2s, 128,128, WREP, R10, wfb, BB+640, D128a);
    conv_mfma<0><<<dim3(4,16,8),  256, 0, stream>>>(D128a,nullptr,128,128, WREP, R11, wfb, BB+704, X128);
    conv_mfma<2><<<dim3(8,32,8),  256, 0, stream>>>(X128, C1s, 256,256, WREP, R12, wfb, BB+768, Y256);
    conv_mfma<0><<<dim3(8,32,8),  256, 0, stream>>>(Y256, nullptr,256,256, WREP, R13, wfb, BB+832, C1s);

    final_k<<<dim3(2048), 256, 0, stream>>>(C1s, wfb, zf, out);
}